// Round 18
// baseline (306.850 us; speedup 1.0000x reference)
//
#include <hip/hip_runtime.h>

#define NN 20000
#define NE 320000
#define CC 128
#define SS 10
#define NWIN 10000  // 2 nodes per window (edge kernel)

typedef __attribute__((ext_vector_type(8))) short short8;
typedef __attribute__((ext_vector_type(4))) float f32x4;

#define MFMA16(a, b, c) __builtin_amdgcn_mfma_f32_16x16x32_bf16(a, b, c, 0, 0, 0)

__device__ __forceinline__ float silu_f(float x) { return x / (1.f + __expf(-x)); }

__device__ __forceinline__ unsigned short f2bf(float x) {  // RNE float->bf16 bits
  unsigned u = __float_as_uint(x);
  unsigned r = u + 0x7FFFu + ((u >> 16) & 1u);
  return (unsigned short)(r >> 16);
}
__device__ __forceinline__ float bf2f(unsigned short h) {
  return __uint_as_float(((unsigned)h) << 16);
}
__device__ __forceinline__ void cvt8(const float* xs, short8& ah, short8& al) {
#pragma unroll
  for (int j = 0; j < 8; ++j) {
    const unsigned short h = f2bf(xs[j]);
    ah[j] = (short)h;
    al[j] = (short)f2bf(xs[j] - bf2f(h));
  }
}

// ---------------- prep: W2 -> transposed bf16 hi/lo [col][k] ----------------
__global__ __launch_bounds__(256) void k_prep_w2(const float* __restrict__ W2,
                                                 unsigned short* __restrict__ w2h,
                                                 unsigned short* __restrict__ w2l) {
  const int i = blockIdx.x * 256 + threadIdx.x;  // grid 64 -> 16384
  if (i < 64 * 256) {
    const int col = i % 256, k = i / 256;  // i == k*256+col
    const float x = W2[i];
    const unsigned short h = f2bf(x);
    w2h[col * 64 + k] = h;
    w2l[col * 64 + k] = f2bf(x - bf2f(h));
  }
}

// ---------------- prep: four 128x128 W -> transposed bf16 hi/lo [col][k] -----
// matrix m at offset m*16384: 0=Wd0 1=Wd1 2=Wp0 3=Wp1
__global__ __launch_bounds__(256) void k_prep_w128(
    const float* __restrict__ Wd0, const float* __restrict__ Wd1,
    const float* __restrict__ Wp0, const float* __restrict__ Wp1,
    unsigned short* __restrict__ wh, unsigned short* __restrict__ wl) {
  const int b = blockIdx.x;       // 0..255
  const int m = b >> 6;           // matrix id
  const int i = (b & 63) * 256 + threadIdx.x;  // 0..16383
  const float* W = (m == 0) ? Wd0 : (m == 1) ? Wd1 : (m == 2) ? Wp0 : Wp1;
  const int k = i >> 7, col = i & 127;
  const float x = W[i];
  const unsigned short h = f2bf(x);
  wh[m * 16384 + col * 128 + k] = h;
  wl[m * 16384 + col * 128 + k] = f2bf(x - bf2f(h));
}

// ------- h = node_feats @ W_up, persistent: W_up in LDS once per block -------
// 512 blocks x 256 threads; thread (c = t&127, p = t>>7) handles channel c of
// nodes win*16 + p*8 + q. Same FMA order per output as the old k_node_h ->
// numerics identical. W_up L2 traffic: 20000*64KB -> 512*64KB.
__global__ __launch_bounds__(256) void k_node_h2(const float* __restrict__ nf,
                                                 const float* __restrict__ W,
                                                 float* __restrict__ h) {
  __shared__ __align__(16) float Ws[128 * 128];  // 64 KB
  __shared__ __align__(16) float rows[16][CC];   // 8 KB
  const int t = threadIdx.x;
  const int c = t & 127, p = t >> 7;
  for (int i = t; i < 16384; i += 256) Ws[i] = W[i];
  __syncthreads();
  for (int win = blockIdx.x; win < NN / 16; win += gridDim.x) {
    const int n0 = win * 16;
#pragma unroll
    for (int q = 0; q < 8; ++q)
      rows[p * 8 + q][c] = nf[(size_t)(n0 + p * 8 + q) * CC + c];
    __syncthreads();
    float acc[8] = {0.f, 0.f, 0.f, 0.f, 0.f, 0.f, 0.f, 0.f};
    for (int k = 0; k < CC; k += 4) {
      const float w0 = Ws[(k + 0) * CC + c];
      const float w1 = Ws[(k + 1) * CC + c];
      const float w2 = Ws[(k + 2) * CC + c];
      const float w3 = Ws[(k + 3) * CC + c];
#pragma unroll
      for (int q = 0; q < 8; ++q) {
        float4 v = *(const float4*)&rows[p * 8 + q][k];
        acc[q] += v.x * w0 + v.y * w1 + v.z * w2 + v.w * w3;
      }
    }
#pragma unroll
    for (int q = 0; q < 8; ++q)
      h[(size_t)(n0 + p * 8 + q) * CC + c] = acc[q];
    __syncthreads();  // rows reused next window
  }
}

// ---------------- CSR build ----------------
__global__ void k_hist(const int* __restrict__ recv, int* __restrict__ cnt) {
  int i = blockIdx.x * blockDim.x + threadIdx.x;
  if (i < NE) atomicAdd(&cnt[recv[i]], 1);
}

__global__ __launch_bounds__(1024) void k_scan2(int* cntcur, int* offs) {
  const int t = threadIdx.x;
  int v[20];
  int tot = 0;
  if (t < 1000) {
#pragma unroll
    for (int i = 0; i < 20; ++i) {
      v[i] = cntcur[t * 20 + i];
      tot += v[i];
    }
  }
  const int lane = t & 63;
  int x = tot;
#pragma unroll
  for (int off = 1; off < 64; off <<= 1) {
    int y = __shfl_up(x, off, 64);
    if (lane >= off) x += y;
  }
  __shared__ int wt[16], wo[16];
  if (lane == 63) wt[t >> 6] = x;
  __syncthreads();
  if (t == 0) {
    int a = 0;
    for (int w = 0; w < 16; ++w) {
      wo[w] = a;
      a += wt[w];
    }
    offs[NN] = a;
  }
  __syncthreads();
  int run = wo[t >> 6] + x - tot;
  if (t < 1000) {
#pragma unroll
    for (int i = 0; i < 20; ++i) {
      offs[t * 20 + i] = run;
      cntcur[t * 20 + i] = run;
      run += v[i];
    }
  }
}

// Scatter edges into receiver-sorted 64B records:
// rec[0..2]=y1*sqrt3, rec[3]=len, rec[4..11]=efeat, int(rec[12])=sender
__global__ void k_fill2(const int* __restrict__ recv, const int* __restrict__ snd,
                        const float* __restrict__ vectors,
                        const float* __restrict__ lengths,
                        const float* __restrict__ efeat, int* __restrict__ cur,
                        float* __restrict__ edata) {
  int i = blockIdx.x * blockDim.x + threadIdx.x;
  if (i < NE) {
    const int r = recv[i];
    const int pos = atomicAdd(&cur[r], 1);
    const float vx = vectors[i * 3 + 0];
    const float vy = vectors[i * 3 + 1];
    const float vz = vectors[i * 3 + 2];
    const float nr = sqrtf(vx * vx + vy * vy + vz * vz) + 1e-9f;
    const float sc = 1.7320508075688772f / nr;
    float4 a = {vx * sc, vy * sc, vz * sc, lengths[i]};
    float4 b = *(const float4*)&efeat[(size_t)i * 8];
    float4 c = *(const float4*)&efeat[(size_t)i * 8 + 4];
    float4 d;
    ((int*)&d)[0] = snd[i];
    d.y = 0.f; d.z = 0.f; d.w = 0.f;
    float* rec = edata + (size_t)pos * 16;
    *(float4*)rec = a;
    *(float4*)(rec + 4) = b;
    *(float4*)(rec + 8) = c;
    *(float4*)(rec + 12) = d;
  }
}

// ---------------- persistent pipelined 2-node-window edge aggregation -------
// r16's k_edge3q verbatim (best measured: 131.8 us). Wave wv owns 32-col
// slice of BOTH w0 and w1 -> each h value fetched once per pass.
__global__ __launch_bounds__(256) void k_edge3q(
    const float* __restrict__ hbuf, const float* __restrict__ W1,
    const float* __restrict__ B1, const unsigned short* __restrict__ w2h,
    const unsigned short* __restrict__ w2l, const int* __restrict__ offs,
    const float* __restrict__ edata, float* __restrict__ sout) {
  __shared__ __align__(16) float W1s[9 * 64];
  __shared__ __align__(16) float B1s[64];
  __shared__ __align__(16) float ed[2][32][20];
  __shared__ __align__(16) unsigned short hidh[32][72];
  __shared__ __align__(16) unsigned short hidl[32][72];

  const int t = threadIdx.x;
  const int l = t & 63, wv = t >> 6, lg = l >> 4, lm = l & 15;

  for (int i = t; i < 576; i += 256) W1s[i] = W1[i];
  if (t < 64) B1s[t] = B1[t];

  short8 B0h[2][2], B0l[2][2], B1h[2][2], B1l[2][2];
#pragma unroll
  for (int ct = 0; ct < 2; ++ct)
#pragma unroll
    for (int s = 0; s < 2; ++s) {
      const int col0 = wv * 32 + ct * 16 + lm;
      const int col1 = 128 + col0;
      B0h[ct][s] = *(const short8*)&w2h[col0 * 64 + s * 32 + lg * 8];
      B0l[ct][s] = *(const short8*)&w2l[col0 * 64 + s * 32 + lg * 8];
      B1h[ct][s] = *(const short8*)&w2h[col1 * 64 + s * 32 + lg * 8];
      B1l[ct][s] = *(const short8*)&w2l[col1 * 64 + s * 32 + lg * 8];
    }

  const int se2 = t >> 2, sq2 = t & 3;

#define CONSUME(GR, A0, A1, HC, YA, YB, YC)                                    \
  do {                                                                         \
    float vv0[2][4], m1[2][4];                                                 \
    _Pragma("unroll") for (int ct = 0; ct < 2; ++ct)                           \
        _Pragma("unroll") for (int r = 0; r < 4; ++r) {                        \
      vv0[ct][r] = (A0)[ct][r] * (HC)[ct][r];                                  \
      m1[ct][r] = (A1)[ct][r] * (HC)[ct][r];                                   \
    }                                                                          \
    const bool fast0 = ((GR) + 16 <= o1);                                      \
    const bool fast1 = ((GR) >= o1) && ((GR) + 16 <= o2);                      \
    if (fast0) {                                                               \
      _Pragma("unroll") for (int ct = 0; ct < 2; ++ct)                         \
          _Pragma("unroll") for (int r = 0; r < 4; ++r) {                      \
        p0[0][ct] += vv0[ct][r];                                               \
        px[0][ct] += m1[ct][r] * (YA)[r];                                      \
        py[0][ct] += m1[ct][r] * (YB)[r];                                      \
        pz[0][ct] += m1[ct][r] * (YC)[r];                                      \
      }                                                                        \
    } else if (fast1) {                                                        \
      _Pragma("unroll") for (int ct = 0; ct < 2; ++ct)                         \
          _Pragma("unroll") for (int r = 0; r < 4; ++r) {                      \
        p0[1][ct] += vv0[ct][r];                                               \
        px[1][ct] += m1[ct][r] * (YA)[r];                                      \
        py[1][ct] += m1[ct][r] * (YB)[r];                                      \
        pz[1][ct] += m1[ct][r] * (YC)[r];                                      \
      }                                                                        \
    } else {                                                                   \
      const int grow0 = (GR) + lg * 4;                                         \
      _Pragma("unroll") for (int sl = 0; sl < 2; ++sl) {                       \
        const int slo = sl ? o1 : o0;                                          \
        const int shi = sl ? o2 : o1;                                          \
        if (shi > (GR) && slo < (GR) + 16) {                                   \
          _Pragma("unroll") for (int r = 0; r < 4; ++r) {                      \
            const bool in = (grow0 + r >= slo) && (grow0 + r < shi);           \
            _Pragma("unroll") for (int ct = 0; ct < 2; ++ct) {                 \
              const float v0 = in ? vv0[ct][r] : 0.f;                          \
              const float m = in ? m1[ct][r] : 0.f;                            \
              p0[sl][ct] += v0;                                                \
              px[sl][ct] += m * (YA)[r];                                       \
              py[sl][ct] += m * (YB)[r];                                       \
              pz[sl][ct] += m * (YC)[r];                                       \
            }                                                                  \
          }                                                                    \
        }                                                                      \
      }                                                                        \
    }                                                                          \
  } while (0)

  __syncthreads();  // W1s/B1s ready (once per block)

  for (int win = blockIdx.x; win < NWIN; win += gridDim.x) {
    const int nb = win * 2;
    const int o0 = offs[nb], o1 = offs[nb + 1], o2 = offs[nb + 2];

    float p0[2][2] = {};
    float px[2][2] = {}, py[2][2] = {}, pz[2][2] = {};

    float4 sreg = {0.f, 0.f, 0.f, 0.f};
    if (t < 128) {
      const int idx = o0 + se2;
      if (idx < o2) sreg = *(const float4*)&edata[(size_t)idx * 16 + sq2 * 4];
      *(float4*)&ed[0][se2][sq2 * 4] = sreg;
      sreg = (float4){0.f, 0.f, 0.f, 0.f};
      const int idx1 = o0 + 32 + se2;
      if (idx1 < o2) sreg = *(const float4*)&edata[(size_t)idx1 * 16 + sq2 * 4];
    }
    __syncthreads();  // ed[0] ready

    const int npass = (o2 - o0 + 31) >> 5;
    for (int p = 0; p < npass; ++p) {
      const int pb = p & 1;
      const int base = o0 + p * 32;
      {  // hid: thread t -> edge e=t&31, k-range [kseg*8, kseg*8+8)
        const int e = t & 31, kseg = t >> 5;
        const int k0 = kseg * 8;
        float ef[9];
#pragma unroll
        for (int r = 0; r < 8; ++r) ef[r] = ed[pb][e][4 + r];
        ef[8] = ed[pb][e][3];
        float4 xa = *(const float4*)&B1s[k0];
        float4 xb = *(const float4*)&B1s[k0 + 4];
#pragma unroll
        for (int r = 0; r < 9; ++r) {
          const float4 wa = *(const float4*)&W1s[r * 64 + k0];
          const float4 wb = *(const float4*)&W1s[r * 64 + k0 + 4];
          xa.x += ef[r] * wa.x; xa.y += ef[r] * wa.y;
          xa.z += ef[r] * wa.z; xa.w += ef[r] * wa.w;
          xb.x += ef[r] * wb.x; xb.y += ef[r] * wb.y;
          xb.z += ef[r] * wb.z; xb.w += ef[r] * wb.w;
        }
        float xs[8];
        xs[0] = silu_f(xa.x); xs[1] = silu_f(xa.y);
        xs[2] = silu_f(xa.z); xs[3] = silu_f(xa.w);
        xs[4] = silu_f(xb.x); xs[5] = silu_f(xb.y);
        xs[6] = silu_f(xb.z); xs[7] = silu_f(xb.w);
        short8 ah, al;
        cvt8(xs, ah, al);
        *(short8*)&hidh[e][k0] = ah;
        *(short8*)&hidl[e][k0] = al;
      }
      __syncthreads();  // B1: hid ready; consume(p-1) finished (prev B2)
      if (t < 128) {
        *(float4*)&ed[pb ^ 1][se2][sq2 * 4] = sreg;
        sreg = (float4){0.f, 0.f, 0.f, 0.f};
        const int idx2 = base + 64 + se2;
        if (idx2 < o2) sreg = *(const float4*)&edata[(size_t)idx2 * 16 + sq2 * 4];
      }
      {
        int sd0[4];
        float ya0[4], yb0[4], yc0[4];
#pragma unroll
        for (int r = 0; r < 4; ++r) {
          const int row = lg * 4 + r;
          sd0[r] = __float_as_int(ed[pb][row][12]);
          ya0[r] = ed[pb][row][0];
          yb0[r] = ed[pb][row][1];
          yc0[r] = ed[pb][row][2];
        }
        float hc0[2][4];
#pragma unroll
        for (int ct = 0; ct < 2; ++ct) {
          const int col = wv * 32 + ct * 16 + lm;
#pragma unroll
          for (int r = 0; r < 4; ++r) hc0[ct][r] = hbuf[(size_t)sd0[r] * CC + col];
        }
        short8 Ah0 = *(const short8*)&hidh[lm][lg * 8];
        short8 Ah1 = *(const short8*)&hidh[lm][32 + lg * 8];
        short8 Al0 = *(const short8*)&hidl[lm][lg * 8];
        short8 Al1 = *(const short8*)&hidl[lm][32 + lg * 8];
        f32x4 a0[2], a1[2];
#pragma unroll
        for (int ct = 0; ct < 2; ++ct) {
          f32x4 a = {0.f, 0.f, 0.f, 0.f};
          a = MFMA16(Ah0, B0h[ct][0], a);
          a = MFMA16(Ah0, B0l[ct][0], a);
          a = MFMA16(Al0, B0h[ct][0], a);
          a = MFMA16(Ah1, B0h[ct][1], a);
          a = MFMA16(Ah1, B0l[ct][1], a);
          a = MFMA16(Al1, B0h[ct][1], a);
          a0[ct] = a;
          f32x4 b = {0.f, 0.f, 0.f, 0.f};
          b = MFMA16(Ah0, B1h[ct][0], b);
          b = MFMA16(Ah0, B1l[ct][0], b);
          b = MFMA16(Al0, B1h[ct][0], b);
          b = MFMA16(Ah1, B1h[ct][1], b);
          b = MFMA16(Ah1, B1l[ct][1], b);
          b = MFMA16(Al1, B1h[ct][1], b);
          a1[ct] = b;
        }
        const bool live1 = (base + 16) < o2;
        if (live1) {
          int sd1[4];
          float ya1[4], yb1[4], yc1[4];
#pragma unroll
          for (int r = 0; r < 4; ++r) {
            const int row = 16 + lg * 4 + r;
            sd1[r] = __float_as_int(ed[pb][row][12]);
            ya1[r] = ed[pb][row][0];
            yb1[r] = ed[pb][row][1];
            yc1[r] = ed[pb][row][2];
          }
          float hc1[2][4];
#pragma unroll
          for (int ct = 0; ct < 2; ++ct) {
            const int col = wv * 32 + ct * 16 + lm;
#pragma unroll
            for (int r = 0; r < 4; ++r) hc1[ct][r] = hbuf[(size_t)sd1[r] * CC + col];
          }
          CONSUME(base, a0, a1, hc0, ya0, yb0, yc0);
          short8 Ch0 = *(const short8*)&hidh[16 + lm][lg * 8];
          short8 Ch1 = *(const short8*)&hidh[16 + lm][32 + lg * 8];
          short8 Cl0 = *(const short8*)&hidl[16 + lm][lg * 8];
          short8 Cl1 = *(const short8*)&hidl[16 + lm][32 + lg * 8];
          f32x4 b0[2], b1[2];
#pragma unroll
          for (int ct = 0; ct < 2; ++ct) {
            f32x4 a = {0.f, 0.f, 0.f, 0.f};
            a = MFMA16(Ch0, B0h[ct][0], a);
            a = MFMA16(Ch0, B0l[ct][0], a);
            a = MFMA16(Cl0, B0h[ct][0], a);
            a = MFMA16(Ch1, B0h[ct][1], a);
            a = MFMA16(Ch1, B0l[ct][1], a);
            a = MFMA16(Cl1, B0h[ct][1], a);
            b0[ct] = a;
            f32x4 b = {0.f, 0.f, 0.f, 0.f};
            b = MFMA16(Ch0, B1h[ct][0], b);
            b = MFMA16(Ch0, B1l[ct][0], b);
            b = MFMA16(Cl0, B1h[ct][0], b);
            b = MFMA16(Ch1, B1h[ct][1], b);
            b = MFMA16(Ch1, B1l[ct][1], b);
            b = MFMA16(Cl1, B1h[ct][1], b);
            b1[ct] = b;
          }
          CONSUME(base + 16, b0, b1, hc1, ya1, yb1, yc1);
        } else {
          CONSUME(base, a0, a1, hc0, ya0, yb0, yc0);
        }
      }
      __syncthreads();  // B2: pass closed (ed[pb], hidh free)
    }

    const float inv = 1.f / 16.f;
#pragma unroll
    for (int sl = 0; sl < 2; ++sl) {
      const int n = nb + sl;
#pragma unroll
      for (int ct = 0; ct < 2; ++ct) {
        const int col = wv * 32 + ct * 16 + lm;
        float v = p0[sl][ct];
        float vx = px[sl][ct], vy = py[sl][ct], vz = pz[sl][ct];
        v += __shfl_xor(v, 16, 64);  v += __shfl_xor(v, 32, 64);
        vx += __shfl_xor(vx, 16, 64); vx += __shfl_xor(vx, 32, 64);
        vy += __shfl_xor(vy, 16, 64); vy += __shfl_xor(vy, 32, 64);
        vz += __shfl_xor(vz, 16, 64); vz += __shfl_xor(vz, 32, 64);
        if (lg == 0) {
          sout[(size_t)n * 512 + col] = v * inv;
          sout[(size_t)n * 512 + 128 + col] = vx * inv;
          sout[(size_t)n * 512 + 256 + col] = vy * inv;
          sout[(size_t)n * 512 + 384 + col] = vz * inv;
        }
      }
    }
  }  // window loop
#undef CONSUME
}

// ---------------- fused downstream via MFMA v2 (unchanged r10) ---------------
__global__ __launch_bounds__(256, 2) void k_down3(
    const float* __restrict__ sbuf, const float* __restrict__ attrs,
    const unsigned short* __restrict__ wbh, const unsigned short* __restrict__ wbl,
    const float* __restrict__ Wprod0, const float* __restrict__ Wprod1,
    const float* __restrict__ Wr1, const float* __restrict__ Wr2,
    const float* __restrict__ Wg, const float* __restrict__ wvv,
    float* __restrict__ out_scalars, float* __restrict__ out_vec,
    float* __restrict__ out_nf) {
  __shared__ __align__(16) char smem[35840];  // union: b(bf16 hi+lo) / h(f32)
  __shared__ int sidx_s[16];
  __shared__ float mh_s[16][17];
  __shared__ float gate_s[16];
  unsigned short* bh = (unsigned short*)smem;       // [4][16][140]
  unsigned short* bl = bh + 8960;                   // [4][16][140]
  float* hX = (float*)smem;                         // [4][16][132]

  const int t = threadIdx.x;
  const int l = t & 63, wv = t >> 6, lg = l >> 4, lm = l & 15;
  const int n0 = blockIdx.x * 16;

  if (t < 16) {
    int si = 0;
#pragma unroll
    for (int s = 0; s < SS; ++s)
      si = (attrs[(size_t)(n0 + t) * SS + s] > 0.5f) ? s : si;
    sidx_s[t] = si;
  }

  short8 Wfh[2][2][4], Wfl[2][2][4];  // [mat][ct][ks]
#pragma unroll
  for (int mat = 0; mat < 2; ++mat)
#pragma unroll
    for (int ct = 0; ct < 2; ++ct)
#pragma unroll
      for (int ks = 0; ks < 4; ++ks) {
        const size_t off =
            (size_t)mat * 16384 + (size_t)(wv * 32 + ct * 16 + lm) * 128 + ks * 32 + lg * 8;
        Wfh[mat][ct][ks] = *(const short8*)&wbh[off];
        Wfl[mat][ct][ks] = *(const short8*)&wbl[off];
      }

  f32x4 acc[4][2];
#pragma unroll 1
  for (int comp = 0; comp < 4; ++comp) {
    short8 Ah[4], Al[4];
#pragma unroll
    for (int ks = 0; ks < 4; ++ks) {
      const size_t so = (size_t)(n0 + lm) * 512 + comp * 128 + ks * 32 + lg * 8;
      const float4 xa = *(const float4*)&sbuf[so];
      const float4 xb = *(const float4*)&sbuf[so + 4];
      float xs[8] = {xa.x, xa.y, xa.z, xa.w, xb.x, xb.y, xb.z, xb.w};
      cvt8(xs, Ah[ks], Al[ks]);
    }
    const int mat = comp ? 1 : 0;
#pragma unroll
    for (int ct = 0; ct < 2; ++ct) {
      f32x4 a = {0.f, 0.f, 0.f, 0.f};
#pragma unroll
      for (int ks = 0; ks < 4; ++ks) {
        a = MFMA16(Ah[ks], Wfh[mat][ct][ks], a);
        a = MFMA16(Ah[ks], Wfl[mat][ct][ks], a);
        a = MFMA16(Al[ks], Wfh[mat][ct][ks], a);
      }
      acc[comp][ct] = a;
    }
  }

#pragma unroll
  for (int ct = 0; ct < 2; ++ct) {
#pragma unroll
    for (int r = 0; r < 4; ++r) {
      const int node = lg * 4 + r;
      const int c = wv * 32 + ct * 16 + lm;
      const int si = sidx_s[node];
      const float a0 = acc[0][ct][r];
      const float ax = acc[1][ct][r], ay = acc[2][ct][r], az = acc[3][ct][r];
      const float dot = ax * ax + ay * ay + az * az;
      const float a2 = a0 * a0;
      const float* w0 = Wprod0 + (size_t)si * 5 * CC;
      const float* w1 = Wprod1 + (size_t)si * 4 * CC;
      const float b0v = w0[c] * a0 + w0[CC + c] * a2 + w0[2 * CC + c] * dot +
                        w0[3 * CC + c] * (a2 * a0) + w0[4 * CC + c] * (a0 * dot);
      const float fac =
          w1[c] + w1[CC + c] * a0 + w1[2 * CC + c] * a2 + w1[3 * CC + c] * dot;
      const float bv[4] = {b0v, ax * fac, ay * fac, az * fac};
#pragma unroll
      for (int m = 0; m < 4; ++m) {
        const int idx = (m * 16 + node) * 140 + c;
        const unsigned short h = f2bf(bv[m]);
        bh[idx] = h;
        bl[idx] = f2bf(bv[m] - bf2f(h));
      }
    }
  }

#pragma unroll
  for (int mat = 0; mat < 2; ++mat)
#pragma unroll
    for (int ct = 0; ct < 2; ++ct)
#pragma unroll
      for (int ks = 0; ks < 4; ++ks) {
        const size_t off = (size_t)(2 + mat) * 16384 +
                           (size_t)(wv * 32 + ct * 16 + lm) * 128 + ks * 32 + lg * 8;
        Wfh[mat][ct][ks] = *(const short8*)&wbh[off];
        Wfl[mat][ct][ks] = *(const short8*)&wbl[off];
      }
  __syncthreads();  // b complete in LDS

  f32x4 acch[4][2];
#pragma unroll 1
  for (int comp = 0; comp < 4; ++comp) {
    short8 Ah[4], Al[4];
#pragma unroll
    for (int ks = 0; ks < 4; ++ks) {
      const int idx = (comp * 16 + lm) * 140 + ks * 32 + lg * 8;
      Ah[ks] = *(const short8*)&bh[idx];
      Al[ks] = *(const short8*)&bl[idx];
    }
    const int mat = comp ? 1 : 0;
#pragma unroll
    for (int ct = 0; ct < 2; ++ct) {
      f32x4 a = {0.f, 0.f, 0.f, 0.f};
#pragma unroll
      for (int ks = 0; ks < 4; ++ks) {
        a = MFMA16(Ah[ks], Wfh[mat][ct][ks], a);
        a = MFMA16(Ah[ks], Wfl[mat][ct][ks], a);
        a = MFMA16(Al[ks], Wfh[mat][ct][ks], a);
      }
      acch[comp][ct] = a;
    }
  }
  __syncthreads();  // all b reads done; smem now reusable as hX

#pragma unroll
  for (int comp = 0; comp < 4; ++comp)
#pragma unroll
    for (int ct = 0; ct < 2; ++ct)
#pragma unroll
      for (int r = 0; r < 4; ++r) {
        const int node = lg * 4 + r;
        const int c = wv * 32 + ct * 16 + lm;
        hX[(comp * 16 + node) * 132 + c] = acch[comp][ct][r];
        out_nf[(size_t)(n0 + node) * 512 + comp * 128 + c] = acch[comp][ct][r];
      }
  __syncthreads();

  {
    const int node = t >> 4, m = t & 15;
    float a = 0.f;
    const float* Xn = &hX[node * 132];
    for (int k = 0; k < CC; k += 4) {
      const float4 h4 = *(const float4*)&Xn[k];
      a += h4.x * Wr1[(k + 0) * 16 + m] + h4.y * Wr1[(k + 1) * 16 + m] +
           h4.z * Wr1[(k + 2) * 16 + m] + h4.w * Wr1[(k + 3) * 16 + m];
    }
    mh_s[node][m] = silu_f(a);
  }
  __syncthreads();
  if (t < 16) {
    float g = 0.f;
#pragma unroll
    for (int m = 0; m < 16; ++m) g += mh_s[t][m] * Wg[m];
    gate_s[t] = silu_f(g);
  }
  __syncthreads();
  {
    const int node = t >> 4, cb = (t & 15) * 8;
#pragma unroll
    for (int j = 0; j < 8; ++j) {
      float a = 0.f;
#pragma unroll
      for (int m = 0; m < 16; ++m) a += mh_s[node][m] * Wr2[m * CC + cb + j];
      out_scalars[(size_t)(n0 + node) * CC + cb + j] = a;
    }
  }
  if (t < 48) {
    const int node = t / 3, i = t % 3;
    float a = 0.f;
    const float* Xn = &hX[((1 + i) * 16 + node) * 132];
    for (int k = 0; k < CC; k += 4) {
      const float4 h4 = *(const float4*)&Xn[k];
      const float4 w4 = *(const float4*)&wvv[k];
      a += h4.x * w4.x + h4.y * w4.y + h4.z * w4.z + h4.w * w4.w;
    }
    out_vec[(size_t)(n0 + node) * 3 + i] = a * gate_s[node];
  }
}

extern "C" void kernel_launch(void* const* d_in, const int* in_sizes, int n_in,
                              void* d_out, int out_size, void* d_ws, size_t ws_size,
                              hipStream_t stream) {
  const float* vectors    = (const float*)d_in[0];
  const float* lengths    = (const float*)d_in[1];
  const float* node_feats = (const float*)d_in[2];
  const float* node_attrs = (const float*)d_in[3];
  const float* edge_feats = (const float*)d_in[4];
  const int*   edge_index = (const int*)d_in[5];
  const float* W_up       = (const float*)d_in[6];
  const float* radial_w1  = (const float*)d_in[7];
  const float* radial_b1  = (const float*)d_in[8];
  const float* radial_w2  = (const float*)d_in[9];
  const float* Wd0        = (const float*)d_in[10];
  const float* Wd1        = (const float*)d_in[11];
  const float* Wprod0     = (const float*)d_in[12];
  const float* Wprod1     = (const float*)d_in[13];
  const float* Wp0        = (const float*)d_in[14];
  const float* Wp1        = (const float*)d_in[15];
  const float* Wr1        = (const float*)d_in[16];
  const float* Wr2        = (const float*)d_in[17];
  const float* Wg         = (const float*)d_in[18];
  const float* wv         = (const float*)d_in[19];

  float* out = (float*)d_out;
  float* out_scalars = out;
  float* out_vec = out + (size_t)NN * CC;
  float* out_nf = out + (size_t)NN * CC + (size_t)NN * 3;
  float* sbuf = out_nf;        // s-scratch in the nf output region
  float* hbuf = out_scalars;   // h-scratch in the scalars output region
                               // (consumed by k_edge3q, overwritten at the END
                               // of k_down3 — stream-ordered, safe)

  // ws (~21 MB): cnt(=cur) | offs | edata | w2h | w2l | wbh(4x) | wbl(4x)
  int* cnt = (int*)d_ws;                              // NN
  int* offs = cnt + NN;                               // NN+4 (pad)
  float* edata = (float*)(offs + NN + 4);             // NE*16 floats
  unsigned short* w2h = (unsigned short*)(edata + (size_t)NE * 16);  // 16384
  unsigned short* w2l = w2h + 16384;                                 // 16384
  unsigned short* wbh = w2l + 16384;                                 // 4*16384
  unsigned short* wbl = wbh + 4 * 16384;                             // 4*16384

  const int* senders = edge_index;
  const int* receivers = edge_index + NE;

  hipMemsetAsync(cnt, 0, NN * sizeof(int), stream);
  k_prep_w2<<<64, 256, 0, stream>>>(radial_w2, w2h, w2l);
  k_prep_w128<<<256, 256, 0, stream>>>(Wd0, Wd1, Wp0, Wp1, wbh, wbl);
  k_node_h2<<<512, 256, 0, stream>>>(node_feats, W_up, hbuf);
  k_hist<<<NE / 256, 256, 0, stream>>>(receivers, cnt);
  k_scan2<<<1, 1024, 0, stream>>>(cnt, offs);
  k_fill2<<<NE / 256, 256, 0, stream>>>(receivers, senders, vectors, lengths,
                                        edge_feats, cnt, edata);
  k_edge3q<<<2048, 256, 0, stream>>>(hbuf, radial_w1, radial_b1, w2h, w2l,
                                     offs, edata, sbuf);
  k_down3<<<NN / 16, 256, 0, stream>>>(sbuf, node_attrs, wbh, wbl, Wprod0,
                                       Wprod1, Wr1, Wr2, Wg, wv,
                                       out_scalars, out_vec, out_nf);
}

// Round 19
// 300.809 us; speedup vs baseline: 1.0201x; 1.0201x over previous
//
#include <hip/hip_runtime.h>

#define NN 20000
#define NE 320000
#define CC 128
#define SS 10
#define NWIN 10000  // 2 nodes per window (edge kernel)

typedef __attribute__((ext_vector_type(8))) short short8;
typedef __attribute__((ext_vector_type(4))) float f32x4;

#define MFMA16(a, b, c) __builtin_amdgcn_mfma_f32_16x16x32_bf16(a, b, c, 0, 0, 0)

__device__ __forceinline__ float silu_f(float x) { return x / (1.f + __expf(-x)); }

__device__ __forceinline__ unsigned short f2bf(float x) {  // RNE float->bf16 bits
  unsigned u = __float_as_uint(x);
  unsigned r = u + 0x7FFFu + ((u >> 16) & 1u);
  return (unsigned short)(r >> 16);
}
__device__ __forceinline__ float bf2f(unsigned short h) {
  return __uint_as_float(((unsigned)h) << 16);
}
__device__ __forceinline__ void cvt8(const float* xs, short8& ah, short8& al) {
#pragma unroll
  for (int j = 0; j < 8; ++j) {
    const unsigned short h = f2bf(xs[j]);
    ah[j] = (short)h;
    al[j] = (short)f2bf(xs[j] - bf2f(h));
  }
}

// ------- fused prep: W2 split | four 128x128 W splits | cnt zeroing ---------
// grid 400: b<64 -> W2 (bf16 hi/lo, [col][k]); 64<=b<320 -> Wd0/Wd1/Wp0/Wp1;
// b>=320 -> zero cnt[NN]. Replaces 3 dispatches (memset + 2 preps) with 1.
__global__ __launch_bounds__(256) void k_prep_all(
    const float* __restrict__ W2, const float* __restrict__ Wd0,
    const float* __restrict__ Wd1, const float* __restrict__ Wp0,
    const float* __restrict__ Wp1, unsigned short* __restrict__ w2h,
    unsigned short* __restrict__ w2l, unsigned short* __restrict__ wh,
    unsigned short* __restrict__ wl, int* __restrict__ cnt) {
  const int b = blockIdx.x;
  if (b < 64) {
    const int i = b * 256 + threadIdx.x;  // 0..16383
    const int col = i % 256, k = i / 256;  // i == k*256+col
    const float x = W2[i];
    const unsigned short h = f2bf(x);
    w2h[col * 64 + k] = h;
    w2l[col * 64 + k] = f2bf(x - bf2f(h));
  } else if (b < 320) {
    const int bb = b - 64;
    const int m = bb >> 6;  // matrix id: 0=Wd0 1=Wd1 2=Wp0 3=Wp1
    const int i = (bb & 63) * 256 + threadIdx.x;  // 0..16383
    const float* W = (m == 0) ? Wd0 : (m == 1) ? Wd1 : (m == 2) ? Wp0 : Wp1;
    const int k = i >> 7, col = i & 127;
    const float x = W[i];
    const unsigned short h = f2bf(x);
    wh[m * 16384 + col * 128 + k] = h;
    wl[m * 16384 + col * 128 + k] = f2bf(x - bf2f(h));
  } else {
    const int i = (b - 320) * 256 + threadIdx.x;
    if (i < NN) cnt[i] = 0;
  }
}

// ------- h = node_feats @ W_up, persistent: W_up in LDS once per block -------
__global__ __launch_bounds__(256) void k_node_h2(const float* __restrict__ nf,
                                                 const float* __restrict__ W,
                                                 float* __restrict__ h) {
  __shared__ __align__(16) float Ws[128 * 128];  // 64 KB
  __shared__ __align__(16) float rows[16][CC];   // 8 KB
  const int t = threadIdx.x;
  const int c = t & 127, p = t >> 7;
  for (int i = t; i < 16384; i += 256) Ws[i] = W[i];
  __syncthreads();
  for (int win = blockIdx.x; win < NN / 16; win += gridDim.x) {
    const int n0 = win * 16;
#pragma unroll
    for (int q = 0; q < 8; ++q)
      rows[p * 8 + q][c] = nf[(size_t)(n0 + p * 8 + q) * CC + c];
    __syncthreads();
    float acc[8] = {0.f, 0.f, 0.f, 0.f, 0.f, 0.f, 0.f, 0.f};
    for (int k = 0; k < CC; k += 4) {
      const float w0 = Ws[(k + 0) * CC + c];
      const float w1 = Ws[(k + 1) * CC + c];
      const float w2 = Ws[(k + 2) * CC + c];
      const float w3 = Ws[(k + 3) * CC + c];
#pragma unroll
      for (int q = 0; q < 8; ++q) {
        float4 v = *(const float4*)&rows[p * 8 + q][k];
        acc[q] += v.x * w0 + v.y * w1 + v.z * w2 + v.w * w3;
      }
    }
#pragma unroll
    for (int q = 0; q < 8; ++q)
      h[(size_t)(n0 + p * 8 + q) * CC + c] = acc[q];
    __syncthreads();  // rows reused next window
  }
}

// ---------------- CSR build ----------------
__global__ void k_hist(const int* __restrict__ recv, int* __restrict__ cnt) {
  int i = blockIdx.x * blockDim.x + threadIdx.x;
  if (i < NE) atomicAdd(&cnt[recv[i]], 1);
}

__global__ __launch_bounds__(1024) void k_scan2(int* cntcur, int* offs) {
  const int t = threadIdx.x;
  int v[20];
  int tot = 0;
  if (t < 1000) {
#pragma unroll
    for (int i = 0; i < 20; ++i) {
      v[i] = cntcur[t * 20 + i];
      tot += v[i];
    }
  }
  const int lane = t & 63;
  int x = tot;
#pragma unroll
  for (int off = 1; off < 64; off <<= 1) {
    int y = __shfl_up(x, off, 64);
    if (lane >= off) x += y;
  }
  __shared__ int wt[16], wo[16];
  if (lane == 63) wt[t >> 6] = x;
  __syncthreads();
  if (t == 0) {
    int a = 0;
    for (int w = 0; w < 16; ++w) {
      wo[w] = a;
      a += wt[w];
    }
    offs[NN] = a;
  }
  __syncthreads();
  int run = wo[t >> 6] + x - tot;
  if (t < 1000) {
#pragma unroll
    for (int i = 0; i < 20; ++i) {
      offs[t * 20 + i] = run;
      cntcur[t * 20 + i] = run;
      run += v[i];
    }
  }
}

// Scatter edges into receiver-sorted 64B records:
// rec[0..2]=y1*sqrt3, rec[3]=len, rec[4..11]=efeat, int(rec[12])=sender
__global__ void k_fill2(const int* __restrict__ recv, const int* __restrict__ snd,
                        const float* __restrict__ vectors,
                        const float* __restrict__ lengths,
                        const float* __restrict__ efeat, int* __restrict__ cur,
                        float* __restrict__ edata) {
  int i = blockIdx.x * blockDim.x + threadIdx.x;
  if (i < NE) {
    const int r = recv[i];
    const int pos = atomicAdd(&cur[r], 1);
    const float vx = vectors[i * 3 + 0];
    const float vy = vectors[i * 3 + 1];
    const float vz = vectors[i * 3 + 2];
    const float nr = sqrtf(vx * vx + vy * vy + vz * vz) + 1e-9f;
    const float sc = 1.7320508075688772f / nr;
    float4 a = {vx * sc, vy * sc, vz * sc, lengths[i]};
    float4 b = *(const float4*)&efeat[(size_t)i * 8];
    float4 c = *(const float4*)&efeat[(size_t)i * 8 + 4];
    float4 d;
    ((int*)&d)[0] = snd[i];
    d.y = 0.f; d.z = 0.f; d.w = 0.f;
    float* rec = edata + (size_t)pos * 16;
    *(float4*)rec = a;
    *(float4*)(rec + 4) = b;
    *(float4*)(rec + 8) = c;
    *(float4*)(rec + 12) = d;
  }
}

// ---------------- persistent pipelined 2-node-window edge aggregation -------
// r16's k_edge3q verbatim (best measured: 131.8 us).
__global__ __launch_bounds__(256) void k_edge3q(
    const float* __restrict__ hbuf, const float* __restrict__ W1,
    const float* __restrict__ B1, const unsigned short* __restrict__ w2h,
    const unsigned short* __restrict__ w2l, const int* __restrict__ offs,
    const float* __restrict__ edata, float* __restrict__ sout) {
  __shared__ __align__(16) float W1s[9 * 64];
  __shared__ __align__(16) float B1s[64];
  __shared__ __align__(16) float ed[2][32][20];
  __shared__ __align__(16) unsigned short hidh[32][72];
  __shared__ __align__(16) unsigned short hidl[32][72];

  const int t = threadIdx.x;
  const int l = t & 63, wv = t >> 6, lg = l >> 4, lm = l & 15;

  for (int i = t; i < 576; i += 256) W1s[i] = W1[i];
  if (t < 64) B1s[t] = B1[t];

  short8 B0h[2][2], B0l[2][2], B1h[2][2], B1l[2][2];
#pragma unroll
  for (int ct = 0; ct < 2; ++ct)
#pragma unroll
    for (int s = 0; s < 2; ++s) {
      const int col0 = wv * 32 + ct * 16 + lm;
      const int col1 = 128 + col0;
      B0h[ct][s] = *(const short8*)&w2h[col0 * 64 + s * 32 + lg * 8];
      B0l[ct][s] = *(const short8*)&w2l[col0 * 64 + s * 32 + lg * 8];
      B1h[ct][s] = *(const short8*)&w2h[col1 * 64 + s * 32 + lg * 8];
      B1l[ct][s] = *(const short8*)&w2l[col1 * 64 + s * 32 + lg * 8];
    }

  const int se2 = t >> 2, sq2 = t & 3;

#define CONSUME(GR, A0, A1, HC, YA, YB, YC)                                    \
  do {                                                                         \
    float vv0[2][4], m1[2][4];                                                 \
    _Pragma("unroll") for (int ct = 0; ct < 2; ++ct)                           \
        _Pragma("unroll") for (int r = 0; r < 4; ++r) {                        \
      vv0[ct][r] = (A0)[ct][r] * (HC)[ct][r];                                  \
      m1[ct][r] = (A1)[ct][r] * (HC)[ct][r];                                   \
    }                                                                          \
    const bool fast0 = ((GR) + 16 <= o1);                                      \
    const bool fast1 = ((GR) >= o1) && ((GR) + 16 <= o2);                      \
    if (fast0) {                                                               \
      _Pragma("unroll") for (int ct = 0; ct < 2; ++ct)                         \
          _Pragma("unroll") for (int r = 0; r < 4; ++r) {                      \
        p0[0][ct] += vv0[ct][r];                                               \
        px[0][ct] += m1[ct][r] * (YA)[r];                                      \
        py[0][ct] += m1[ct][r] * (YB)[r];                                      \
        pz[0][ct] += m1[ct][r] * (YC)[r];                                      \
      }                                                                        \
    } else if (fast1) {                                                        \
      _Pragma("unroll") for (int ct = 0; ct < 2; ++ct)                         \
          _Pragma("unroll") for (int r = 0; r < 4; ++r) {                      \
        p0[1][ct] += vv0[ct][r];                                               \
        px[1][ct] += m1[ct][r] * (YA)[r];                                      \
        py[1][ct] += m1[ct][r] * (YB)[r];                                      \
        pz[1][ct] += m1[ct][r] * (YC)[r];                                      \
      }                                                                        \
    } else {                                                                   \
      const int grow0 = (GR) + lg * 4;                                         \
      _Pragma("unroll") for (int sl = 0; sl < 2; ++sl) {                       \
        const int slo = sl ? o1 : o0;                                          \
        const int shi = sl ? o2 : o1;                                          \
        if (shi > (GR) && slo < (GR) + 16) {                                   \
          _Pragma("unroll") for (int r = 0; r < 4; ++r) {                      \
            const bool in = (grow0 + r >= slo) && (grow0 + r < shi);           \
            _Pragma("unroll") for (int ct = 0; ct < 2; ++ct) {                 \
              const float v0 = in ? vv0[ct][r] : 0.f;                          \
              const float m = in ? m1[ct][r] : 0.f;                            \
              p0[sl][ct] += v0;                                                \
              px[sl][ct] += m * (YA)[r];                                       \
              py[sl][ct] += m * (YB)[r];                                       \
              pz[sl][ct] += m * (YC)[r];                                       \
            }                                                                  \
          }                                                                    \
        }                                                                      \
      }                                                                        \
    }                                                                          \
  } while (0)

  __syncthreads();  // W1s/B1s ready (once per block)

  for (int win = blockIdx.x; win < NWIN; win += gridDim.x) {
    const int nb = win * 2;
    const int o0 = offs[nb], o1 = offs[nb + 1], o2 = offs[nb + 2];

    float p0[2][2] = {};
    float px[2][2] = {}, py[2][2] = {}, pz[2][2] = {};

    float4 sreg = {0.f, 0.f, 0.f, 0.f};
    if (t < 128) {
      const int idx = o0 + se2;
      if (idx < o2) sreg = *(const float4*)&edata[(size_t)idx * 16 + sq2 * 4];
      *(float4*)&ed[0][se2][sq2 * 4] = sreg;
      sreg = (float4){0.f, 0.f, 0.f, 0.f};
      const int idx1 = o0 + 32 + se2;
      if (idx1 < o2) sreg = *(const float4*)&edata[(size_t)idx1 * 16 + sq2 * 4];
    }
    __syncthreads();  // ed[0] ready

    const int npass = (o2 - o0 + 31) >> 5;
    for (int p = 0; p < npass; ++p) {
      const int pb = p & 1;
      const int base = o0 + p * 32;
      {  // hid: thread t -> edge e=t&31, k-range [kseg*8, kseg*8+8)
        const int e = t & 31, kseg = t >> 5;
        const int k0 = kseg * 8;
        float ef[9];
#pragma unroll
        for (int r = 0; r < 8; ++r) ef[r] = ed[pb][e][4 + r];
        ef[8] = ed[pb][e][3];
        float4 xa = *(const float4*)&B1s[k0];
        float4 xb = *(const float4*)&B1s[k0 + 4];
#pragma unroll
        for (int r = 0; r < 9; ++r) {
          const float4 wa = *(const float4*)&W1s[r * 64 + k0];
          const float4 wb = *(const float4*)&W1s[r * 64 + k0 + 4];
          xa.x += ef[r] * wa.x; xa.y += ef[r] * wa.y;
          xa.z += ef[r] * wa.z; xa.w += ef[r] * wa.w;
          xb.x += ef[r] * wb.x; xb.y += ef[r] * wb.y;
          xb.z += ef[r] * wb.z; xb.w += ef[r] * wb.w;
        }
        float xs[8];
        xs[0] = silu_f(xa.x); xs[1] = silu_f(xa.y);
        xs[2] = silu_f(xa.z); xs[3] = silu_f(xa.w);
        xs[4] = silu_f(xb.x); xs[5] = silu_f(xb.y);
        xs[6] = silu_f(xb.z); xs[7] = silu_f(xb.w);
        short8 ah, al;
        cvt8(xs, ah, al);
        *(short8*)&hidh[e][k0] = ah;
        *(short8*)&hidl[e][k0] = al;
      }
      __syncthreads();  // B1: hid ready; consume(p-1) finished (prev B2)
      if (t < 128) {
        *(float4*)&ed[pb ^ 1][se2][sq2 * 4] = sreg;
        sreg = (float4){0.f, 0.f, 0.f, 0.f};
        const int idx2 = base + 64 + se2;
        if (idx2 < o2) sreg = *(const float4*)&edata[(size_t)idx2 * 16 + sq2 * 4];
      }
      {
        int sd0[4];
        float ya0[4], yb0[4], yc0[4];
#pragma unroll
        for (int r = 0; r < 4; ++r) {
          const int row = lg * 4 + r;
          sd0[r] = __float_as_int(ed[pb][row][12]);
          ya0[r] = ed[pb][row][0];
          yb0[r] = ed[pb][row][1];
          yc0[r] = ed[pb][row][2];
        }
        float hc0[2][4];
#pragma unroll
        for (int ct = 0; ct < 2; ++ct) {
          const int col = wv * 32 + ct * 16 + lm;
#pragma unroll
          for (int r = 0; r < 4; ++r) hc0[ct][r] = hbuf[(size_t)sd0[r] * CC + col];
        }
        short8 Ah0 = *(const short8*)&hidh[lm][lg * 8];
        short8 Ah1 = *(const short8*)&hidh[lm][32 + lg * 8];
        short8 Al0 = *(const short8*)&hidl[lm][lg * 8];
        short8 Al1 = *(const short8*)&hidl[lm][32 + lg * 8];
        f32x4 a0[2], a1[2];
#pragma unroll
        for (int ct = 0; ct < 2; ++ct) {
          f32x4 a = {0.f, 0.f, 0.f, 0.f};
          a = MFMA16(Ah0, B0h[ct][0], a);
          a = MFMA16(Ah0, B0l[ct][0], a);
          a = MFMA16(Al0, B0h[ct][0], a);
          a = MFMA16(Ah1, B0h[ct][1], a);
          a = MFMA16(Ah1, B0l[ct][1], a);
          a = MFMA16(Al1, B0h[ct][1], a);
          a0[ct] = a;
          f32x4 b = {0.f, 0.f, 0.f, 0.f};
          b = MFMA16(Ah0, B1h[ct][0], b);
          b = MFMA16(Ah0, B1l[ct][0], b);
          b = MFMA16(Al0, B1h[ct][0], b);
          b = MFMA16(Ah1, B1h[ct][1], b);
          b = MFMA16(Ah1, B1l[ct][1], b);
          b = MFMA16(Al1, B1h[ct][1], b);
          a1[ct] = b;
        }
        const bool live1 = (base + 16) < o2;
        if (live1) {
          int sd1[4];
          float ya1[4], yb1[4], yc1[4];
#pragma unroll
          for (int r = 0; r < 4; ++r) {
            const int row = 16 + lg * 4 + r;
            sd1[r] = __float_as_int(ed[pb][row][12]);
            ya1[r] = ed[pb][row][0];
            yb1[r] = ed[pb][row][1];
            yc1[r] = ed[pb][row][2];
          }
          float hc1[2][4];
#pragma unroll
          for (int ct = 0; ct < 2; ++ct) {
            const int col = wv * 32 + ct * 16 + lm;
#pragma unroll
            for (int r = 0; r < 4; ++r) hc1[ct][r] = hbuf[(size_t)sd1[r] * CC + col];
          }
          CONSUME(base, a0, a1, hc0, ya0, yb0, yc0);
          short8 Ch0 = *(const short8*)&hidh[16 + lm][lg * 8];
          short8 Ch1 = *(const short8*)&hidh[16 + lm][32 + lg * 8];
          short8 Cl0 = *(const short8*)&hidl[16 + lm][lg * 8];
          short8 Cl1 = *(const short8*)&hidl[16 + lm][32 + lg * 8];
          f32x4 b0[2], b1[2];
#pragma unroll
          for (int ct = 0; ct < 2; ++ct) {
            f32x4 a = {0.f, 0.f, 0.f, 0.f};
            a = MFMA16(Ch0, B0h[ct][0], a);
            a = MFMA16(Ch0, B0l[ct][0], a);
            a = MFMA16(Cl0, B0h[ct][0], a);
            a = MFMA16(Ch1, B0h[ct][1], a);
            a = MFMA16(Ch1, B0l[ct][1], a);
            a = MFMA16(Cl1, B0h[ct][1], a);
            b0[ct] = a;
            f32x4 b = {0.f, 0.f, 0.f, 0.f};
            b = MFMA16(Ch0, B1h[ct][0], b);
            b = MFMA16(Ch0, B1l[ct][0], b);
            b = MFMA16(Cl0, B1h[ct][0], b);
            b = MFMA16(Ch1, B1h[ct][1], b);
            b = MFMA16(Ch1, B1l[ct][1], b);
            b = MFMA16(Cl1, B1h[ct][1], b);
            b1[ct] = b;
          }
          CONSUME(base + 16, b0, b1, hc1, ya1, yb1, yc1);
        } else {
          CONSUME(base, a0, a1, hc0, ya0, yb0, yc0);
        }
      }
      __syncthreads();  // B2: pass closed (ed[pb], hidh free)
    }

    const float inv = 1.f / 16.f;
#pragma unroll
    for (int sl = 0; sl < 2; ++sl) {
      const int n = nb + sl;
#pragma unroll
      for (int ct = 0; ct < 2; ++ct) {
        const int col = wv * 32 + ct * 16 + lm;
        float v = p0[sl][ct];
        float vx = px[sl][ct], vy = py[sl][ct], vz = pz[sl][ct];
        v += __shfl_xor(v, 16, 64);  v += __shfl_xor(v, 32, 64);
        vx += __shfl_xor(vx, 16, 64); vx += __shfl_xor(vx, 32, 64);
        vy += __shfl_xor(vy, 16, 64); vy += __shfl_xor(vy, 32, 64);
        vz += __shfl_xor(vz, 16, 64); vz += __shfl_xor(vz, 32, 64);
        if (lg == 0) {
          sout[(size_t)n * 512 + col] = v * inv;
          sout[(size_t)n * 512 + 128 + col] = vx * inv;
          sout[(size_t)n * 512 + 256 + col] = vy * inv;
          sout[(size_t)n * 512 + 384 + col] = vz * inv;
        }
      }
    }
  }  // window loop
#undef CONSUME
}

// ---------------- fused downstream via MFMA v2 (unchanged r10) ---------------
__global__ __launch_bounds__(256, 2) void k_down3(
    const float* __restrict__ sbuf, const float* __restrict__ attrs,
    const unsigned short* __restrict__ wbh, const unsigned short* __restrict__ wbl,
    const float* __restrict__ Wprod0, const float* __restrict__ Wprod1,
    const float* __restrict__ Wr1, const float* __restrict__ Wr2,
    const float* __restrict__ Wg, const float* __restrict__ wvv,
    float* __restrict__ out_scalars, float* __restrict__ out_vec,
    float* __restrict__ out_nf) {
  __shared__ __align__(16) char smem[35840];  // union: b(bf16 hi+lo) / h(f32)
  __shared__ int sidx_s[16];
  __shared__ float mh_s[16][17];
  __shared__ float gate_s[16];
  unsigned short* bh = (unsigned short*)smem;       // [4][16][140]
  unsigned short* bl = bh + 8960;                   // [4][16][140]
  float* hX = (float*)smem;                         // [4][16][132]

  const int t = threadIdx.x;
  const int l = t & 63, wv = t >> 6, lg = l >> 4, lm = l & 15;
  const int n0 = blockIdx.x * 16;

  if (t < 16) {
    int si = 0;
#pragma unroll
    for (int s = 0; s < SS; ++s)
      si = (attrs[(size_t)(n0 + t) * SS + s] > 0.5f) ? s : si;
    sidx_s[t] = si;
  }

  short8 Wfh[2][2][4], Wfl[2][2][4];  // [mat][ct][ks]
#pragma unroll
  for (int mat = 0; mat < 2; ++mat)
#pragma unroll
    for (int ct = 0; ct < 2; ++ct)
#pragma unroll
      for (int ks = 0; ks < 4; ++ks) {
        const size_t off =
            (size_t)mat * 16384 + (size_t)(wv * 32 + ct * 16 + lm) * 128 + ks * 32 + lg * 8;
        Wfh[mat][ct][ks] = *(const short8*)&wbh[off];
        Wfl[mat][ct][ks] = *(const short8*)&wbl[off];
      }

  f32x4 acc[4][2];
#pragma unroll 1
  for (int comp = 0; comp < 4; ++comp) {
    short8 Ah[4], Al[4];
#pragma unroll
    for (int ks = 0; ks < 4; ++ks) {
      const size_t so = (size_t)(n0 + lm) * 512 + comp * 128 + ks * 32 + lg * 8;
      const float4 xa = *(const float4*)&sbuf[so];
      const float4 xb = *(const float4*)&sbuf[so + 4];
      float xs[8] = {xa.x, xa.y, xa.z, xa.w, xb.x, xb.y, xb.z, xb.w};
      cvt8(xs, Ah[ks], Al[ks]);
    }
    const int mat = comp ? 1 : 0;
#pragma unroll
    for (int ct = 0; ct < 2; ++ct) {
      f32x4 a = {0.f, 0.f, 0.f, 0.f};
#pragma unroll
      for (int ks = 0; ks < 4; ++ks) {
        a = MFMA16(Ah[ks], Wfh[mat][ct][ks], a);
        a = MFMA16(Ah[ks], Wfl[mat][ct][ks], a);
        a = MFMA16(Al[ks], Wfh[mat][ct][ks], a);
      }
      acc[comp][ct] = a;
    }
  }

#pragma unroll
  for (int ct = 0; ct < 2; ++ct) {
#pragma unroll
    for (int r = 0; r < 4; ++r) {
      const int node = lg * 4 + r;
      const int c = wv * 32 + ct * 16 + lm;
      const int si = sidx_s[node];
      const float a0 = acc[0][ct][r];
      const float ax = acc[1][ct][r], ay = acc[2][ct][r], az = acc[3][ct][r];
      const float dot = ax * ax + ay * ay + az * az;
      const float a2 = a0 * a0;
      const float* w0 = Wprod0 + (size_t)si * 5 * CC;
      const float* w1 = Wprod1 + (size_t)si * 4 * CC;
      const float b0v = w0[c] * a0 + w0[CC + c] * a2 + w0[2 * CC + c] * dot +
                        w0[3 * CC + c] * (a2 * a0) + w0[4 * CC + c] * (a0 * dot);
      const float fac =
          w1[c] + w1[CC + c] * a0 + w1[2 * CC + c] * a2 + w1[3 * CC + c] * dot;
      const float bv[4] = {b0v, ax * fac, ay * fac, az * fac};
#pragma unroll
      for (int m = 0; m < 4; ++m) {
        const int idx = (m * 16 + node) * 140 + c;
        const unsigned short h = f2bf(bv[m]);
        bh[idx] = h;
        bl[idx] = f2bf(bv[m] - bf2f(h));
      }
    }
  }

#pragma unroll
  for (int mat = 0; mat < 2; ++mat)
#pragma unroll
    for (int ct = 0; ct < 2; ++ct)
#pragma unroll
      for (int ks = 0; ks < 4; ++ks) {
        const size_t off = (size_t)(2 + mat) * 16384 +
                           (size_t)(wv * 32 + ct * 16 + lm) * 128 + ks * 32 + lg * 8;
        Wfh[mat][ct][ks] = *(const short8*)&wbh[off];
        Wfl[mat][ct][ks] = *(const short8*)&wbl[off];
      }
  __syncthreads();  // b complete in LDS

  f32x4 acch[4][2];
#pragma unroll 1
  for (int comp = 0; comp < 4; ++comp) {
    short8 Ah[4], Al[4];
#pragma unroll
    for (int ks = 0; ks < 4; ++ks) {
      const int idx = (comp * 16 + lm) * 140 + ks * 32 + lg * 8;
      Ah[ks] = *(const short8*)&bh[idx];
      Al[ks] = *(const short8*)&bl[idx];
    }
    const int mat = comp ? 1 : 0;
#pragma unroll
    for (int ct = 0; ct < 2; ++ct) {
      f32x4 a = {0.f, 0.f, 0.f, 0.f};
#pragma unroll
      for (int ks = 0; ks < 4; ++ks) {
        a = MFMA16(Ah[ks], Wfh[mat][ct][ks], a);
        a = MFMA16(Ah[ks], Wfl[mat][ct][ks], a);
        a = MFMA16(Al[ks], Wfh[mat][ct][ks], a);
      }
      acch[comp][ct] = a;
    }
  }
  __syncthreads();  // all b reads done; smem now reusable as hX

#pragma unroll
  for (int comp = 0; comp < 4; ++comp)
#pragma unroll
    for (int ct = 0; ct < 2; ++ct)
#pragma unroll
      for (int r = 0; r < 4; ++r) {
        const int node = lg * 4 + r;
        const int c = wv * 32 + ct * 16 + lm;
        hX[(comp * 16 + node) * 132 + c] = acch[comp][ct][r];
        out_nf[(size_t)(n0 + node) * 512 + comp * 128 + c] = acch[comp][ct][r];
      }
  __syncthreads();

  {
    const int node = t >> 4, m = t & 15;
    float a = 0.f;
    const float* Xn = &hX[node * 132];
    for (int k = 0; k < CC; k += 4) {
      const float4 h4 = *(const float4*)&Xn[k];
      a += h4.x * Wr1[(k + 0) * 16 + m] + h4.y * Wr1[(k + 1) * 16 + m] +
           h4.z * Wr1[(k + 2) * 16 + m] + h4.w * Wr1[(k + 3) * 16 + m];
    }
    mh_s[node][m] = silu_f(a);
  }
  __syncthreads();
  if (t < 16) {
    float g = 0.f;
#pragma unroll
    for (int m = 0; m < 16; ++m) g += mh_s[t][m] * Wg[m];
    gate_s[t] = silu_f(g);
  }
  __syncthreads();
  {
    const int node = t >> 4, cb = (t & 15) * 8;
#pragma unroll
    for (int j = 0; j < 8; ++j) {
      float a = 0.f;
#pragma unroll
      for (int m = 0; m < 16; ++m) a += mh_s[node][m] * Wr2[m * CC + cb + j];
      out_scalars[(size_t)(n0 + node) * CC + cb + j] = a;
    }
  }
  if (t < 48) {
    const int node = t / 3, i = t % 3;
    float a = 0.f;
    const float* Xn = &hX[((1 + i) * 16 + node) * 132];
    for (int k = 0; k < CC; k += 4) {
      const float4 h4 = *(const float4*)&Xn[k];
      const float4 w4 = *(const float4*)&wvv[k];
      a += h4.x * w4.x + h4.y * w4.y + h4.z * w4.z + h4.w * w4.w;
    }
    out_vec[(size_t)(n0 + node) * 3 + i] = a * gate_s[node];
  }
}

extern "C" void kernel_launch(void* const* d_in, const int* in_sizes, int n_in,
                              void* d_out, int out_size, void* d_ws, size_t ws_size,
                              hipStream_t stream) {
  const float* vectors    = (const float*)d_in[0];
  const float* lengths    = (const float*)d_in[1];
  const float* node_feats = (const float*)d_in[2];
  const float* node_attrs = (const float*)d_in[3];
  const float* edge_feats = (const float*)d_in[4];
  const int*   edge_index = (const int*)d_in[5];
  const float* W_up       = (const float*)d_in[6];
  const float* radial_w1  = (const float*)d_in[7];
  const float* radial_b1  = (const float*)d_in[8];
  const float* radial_w2  = (const float*)d_in[9];
  const float* Wd0        = (const float*)d_in[10];
  const float* Wd1        = (const float*)d_in[11];
  const float* Wprod0     = (const float*)d_in[12];
  const float* Wprod1     = (const float*)d_in[13];
  const float* Wp0        = (const float*)d_in[14];
  const float* Wp1        = (const float*)d_in[15];
  const float* Wr1        = (const float*)d_in[16];
  const float* Wr2        = (const float*)d_in[17];
  const float* Wg         = (const float*)d_in[18];
  const float* wv         = (const float*)d_in[19];

  float* out = (float*)d_out;
  float* out_scalars = out;
  float* out_vec = out + (size_t)NN * CC;
  float* out_nf = out + (size_t)NN * CC + (size_t)NN * 3;
  float* sbuf = out_nf;        // s-scratch in the nf output region
  float* hbuf = out_scalars;   // h-scratch in the scalars output region
                               // (consumed by k_edge3q, overwritten at the END
                               // of k_down3 — stream-ordered, safe)

  // ws (~21 MB): cnt(=cur) | offs | edata | w2h | w2l | wbh(4x) | wbl(4x)
  int* cnt = (int*)d_ws;                              // NN
  int* offs = cnt + NN;                               // NN+4 (pad)
  float* edata = (float*)(offs + NN + 4);             // NE*16 floats
  unsigned short* w2h = (unsigned short*)(edata + (size_t)NE * 16);  // 16384
  unsigned short* w2l = w2h + 16384;                                 // 16384
  unsigned short* wbh = w2l + 16384;                                 // 4*16384
  unsigned short* wbl = wbh + 4 * 16384;                             // 4*16384

  const int* senders = edge_index;
  const int* receivers = edge_index + NE;

  k_prep_all<<<400, 256, 0, stream>>>(radial_w2, Wd0, Wd1, Wp0, Wp1,
                                      w2h, w2l, wbh, wbl, cnt);
  k_node_h2<<<512, 256, 0, stream>>>(node_feats, W_up, hbuf);
  k_hist<<<NE / 256, 256, 0, stream>>>(receivers, cnt);
  k_scan2<<<1, 1024, 0, stream>>>(cnt, offs);
  k_fill2<<<NE / 256, 256, 0, stream>>>(receivers, senders, vectors, lengths,
                                        edge_feats, cnt, edata);
  k_edge3q<<<2048, 256, 0, stream>>>(hbuf, radial_w1, radial_b1, w2h, w2l,
                                     offs, edata, sbuf);
  k_down3<<<NN / 16, 256, 0, stream>>>(sbuf, node_attrs, wbh, wbl, Wprod0,
                                       Wprod1, Wr1, Wr2, Wg, wv,
                                       out_scalars, out_vec, out_nf);
}